// Round 3
// baseline (679.041 us; speedup 1.0000x reference)
//
#include <hip/hip_runtime.h>

#define NN 131072
#define DD 64
#define KK 1024
#define KT 256   // codebook entries per LDS tile: 256*64*4 = 64 KB

// numpy pairwise sum (n=64, contiguous): a_i = fl(v_i*v_i);
// r[j] = a[j] (+seq) a[j+8] ... a[j+56]; res = ((r0+r1)+(r2+r3))+((r4+r5)+(r6+r7))
__device__ __forceinline__ float np_sumsq64(const float* v) {
    float r[8];
#pragma unroll
    for (int j = 0; j < 8; ++j) r[j] = __fmul_rn(v[j], v[j]);
#pragma unroll
    for (int i = 8; i < 64; i += 8) {
#pragma unroll
        for (int j = 0; j < 8; ++j)
            r[j] = __fadd_rn(r[j], __fmul_rn(v[i + j], v[i + j]));
    }
    return __fadd_rn(__fadd_rn(__fadd_rn(r[0], r[1]), __fadd_rn(r[2], r[3])),
                     __fadd_rn(__fadd_rn(r[4], r[5]), __fadd_rn(r[6], r[7])));
}

// ---------------- codebook squared norms (numpy-pairwise order) ----------------
__global__ void vq_se(const float* __restrict__ cb, float* __restrict__ se) {
    int k = blockIdx.x * blockDim.x + threadIdx.x;
    if (k >= KK) return;
    float e[DD];
    const float4* p = (const float4*)(cb + (size_t)k * DD);
#pragma unroll
    for (int i = 0; i < DD / 4; ++i) {
        float4 v = p[i];
        e[4 * i + 0] = v.x; e[4 * i + 1] = v.y; e[4 * i + 2] = v.z; e[4 * i + 3] = v.w;
    }
    se[k] = np_sumsq64(e);
}

// ---------------- argmin over codebook ----------------
// 256 threads/block, 1 row/thread, 512 blocks -> 2 blocks/CU (64KB LDS), 2 waves/SIMD.
__global__ __launch_bounds__(256)
void vq_argmin(const float* __restrict__ x, const float* __restrict__ cb,
               const float* __restrict__ se, int* __restrict__ idx,
               float* __restrict__ idx_f) {
    __shared__ float ecache[KT * DD];   // 64 KB
    __shared__ float secache[KT];

    const int tid = threadIdx.x;
    const int row = blockIdx.x * 256 + tid;

    float a[DD];
    {
        const float4* p = (const float4*)(x + (size_t)row * DD);
#pragma unroll
        for (int i = 0; i < DD / 4; ++i) {
            float4 v = p[i];
            a[4 * i + 0] = v.x; a[4 * i + 1] = v.y; a[4 * i + 2] = v.z; a[4 * i + 3] = v.w;
        }
    }

    const float sa = np_sumsq64(a);   // bit-matches np.sum(x**2, axis=1)

    float best = 3.4e38f;
    int   bi = 0;

    for (int t = 0; t < KK / KT; ++t) {
        __syncthreads();
        // stage codebook tile into LDS, coalesced float4 (16 per thread)
        const float4* src = (const float4*)(cb + (size_t)t * KT * DD);
        float4* dst = (float4*)ecache;
#pragma unroll
        for (int j = 0; j < (KT * DD / 4) / 256; ++j)
            dst[j * 256 + tid] = src[j * 256 + tid];
        secache[tid] = se[t * KT + tid];
        __syncthreads();

        // 4 codebook entries at a time: 4 independent sequential-fma chains
        // (each chain matches BLAS sgemm k-order accumulation exactly)
        for (int kk = 0; kk < KT; kk += 4) {
            const float4* e0 = (const float4*)(ecache + (kk + 0) * DD);
            const float4* e1 = (const float4*)(ecache + (kk + 1) * DD);
            const float4* e2 = (const float4*)(ecache + (kk + 2) * DD);
            const float4* e3 = (const float4*)(ecache + (kk + 3) * DD);
            float c0 = 0.f, c1 = 0.f, c2 = 0.f, c3 = 0.f;
#pragma unroll
            for (int i = 0; i < DD / 4; ++i) {
                float ax = a[4 * i + 0], ay = a[4 * i + 1];
                float az = a[4 * i + 2], aw = a[4 * i + 3];
                float4 v0 = e0[i];
                c0 = fmaf(ax, v0.x, c0); c0 = fmaf(ay, v0.y, c0);
                c0 = fmaf(az, v0.z, c0); c0 = fmaf(aw, v0.w, c0);
                float4 v1 = e1[i];
                c1 = fmaf(ax, v1.x, c1); c1 = fmaf(ay, v1.y, c1);
                c1 = fmaf(az, v1.z, c1); c1 = fmaf(aw, v1.w, c1);
                float4 v2 = e2[i];
                c2 = fmaf(ax, v2.x, c2); c2 = fmaf(ay, v2.y, c2);
                c2 = fmaf(az, v2.z, c2); c2 = fmaf(aw, v2.w, c2);
                float4 v3 = e3[i];
                c3 = fmaf(ax, v3.x, c3); c3 = fmaf(ay, v3.y, c3);
                c3 = fmaf(az, v3.z, c3); c3 = fmaf(aw, v3.w, c3);
            }
            // distances = fl(fl(sa+se) - fl(2*dot)), argmin first-occurrence
            int kbase = t * KT + kk;
            float d0 = __fsub_rn(__fadd_rn(sa, secache[kk + 0]), __fmul_rn(2.f, c0));
            if (d0 < best) { best = d0; bi = kbase + 0; }
            float d1 = __fsub_rn(__fadd_rn(sa, secache[kk + 1]), __fmul_rn(2.f, c1));
            if (d1 < best) { best = d1; bi = kbase + 1; }
            float d2 = __fsub_rn(__fadd_rn(sa, secache[kk + 2]), __fmul_rn(2.f, c2));
            if (d2 < best) { best = d2; bi = kbase + 2; }
            float d3 = __fsub_rn(__fadd_rn(sa, secache[kk + 3]), __fmul_rn(2.f, c3));
            if (d3 < best) { best = d3; bi = kbase + 3; }
        }
    }

    idx[row]   = bi;
    idx_f[row] = (float)bi;
}

// ---------------- gather + straight-through + loss partials ----------------
__global__ __launch_bounds__(256)
void vq_quant(const float* __restrict__ x, const float* __restrict__ cb,
              const int* __restrict__ idx, float* __restrict__ qout,
              double* __restrict__ acc) {
    const int nvec = NN * DD / 4;
    const int stride = gridDim.x * blockDim.x;
    float local = 0.f;
    for (int j = blockIdx.x * blockDim.x + threadIdx.x; j < nvec; j += stride) {
        int row = j >> 4;           // 16 float4 per row
        int d4  = j & 15;
        int k   = idx[row];
        float4 xv = ((const float4*)x)[j];
        float4 qv = ((const float4*)cb)[(k << 4) | d4];
        float dx = __fsub_rn(qv.x, xv.x);
        float dy = __fsub_rn(qv.y, xv.y);
        float dz = __fsub_rn(qv.z, xv.z);
        float dw = __fsub_rn(qv.w, xv.w);
        float4 o;
        o.x = __fadd_rn(xv.x, dx);
        o.y = __fadd_rn(xv.y, dy);
        o.z = __fadd_rn(xv.z, dz);
        o.w = __fadd_rn(xv.w, dw);
        ((float4*)qout)[j] = o;
        local = fmaf(dx, dx, local);
        local = fmaf(dy, dy, local);
        local = fmaf(dz, dz, local);
        local = fmaf(dw, dw, local);
    }
#pragma unroll
    for (int off = 32; off > 0; off >>= 1)
        local += __shfl_down(local, off);
    __shared__ float wsum[4];
    if ((threadIdx.x & 63) == 0) wsum[threadIdx.x >> 6] = local;
    __syncthreads();
    if (threadIdx.x == 0) {
        float s = wsum[0] + wsum[1] + wsum[2] + wsum[3];
        atomicAdd(acc, (double)s);
    }
}

// ---------------- finalize loss ----------------
__global__ void vq_loss(const double* __restrict__ acc, float* __restrict__ out) {
    out[0] = (float)(acc[0] * 1.25 / (double)((size_t)NN * DD));
}

extern "C" void kernel_launch(void* const* d_in, const int* in_sizes, int n_in,
                              void* d_out, int out_size, void* d_ws, size_t ws_size,
                              hipStream_t stream) {
    const float* x  = (const float*)d_in[0];
    const float* cb = (const float*)d_in[1];
    float* out = (float*)d_out;

    double* acc = (double*)d_ws;                      // 8B accumulator (zeroed below)
    float*  se  = (float*)((char*)d_ws + 64);         // 1024 floats
    int*    idx = (int*)((char*)d_ws + 64 + 4096);    // 131072 ints

    hipMemsetAsync(d_ws, 0, 64, stream);

    vq_se<<<4, 256, 0, stream>>>(cb, se);
    vq_argmin<<<NN / 256, 256, 0, stream>>>(x, cb, se, idx, out + 1 + (size_t)NN * DD);
    vq_quant<<<2048, 256, 0, stream>>>(x, cb, idx, out + 1, acc);
    vq_loss<<<1, 1, 0, stream>>>(acc, out);
}

// Round 5
// 337.041 us; speedup vs baseline: 2.0147x; 2.0147x over previous
//
#include <hip/hip_runtime.h>

#define NN 131072
#define DD 64
#define KK 1024
#define BR 128        // rows per block
#define BC 128        // codebook entries per LDS tile
#define NTILES (KK / BC)

// numpy pairwise sum (n=64, contiguous): a_i = fl(v_i*v_i);
// r[j] = a[j] (+seq) a[j+8] ... a[j+56]; res = ((r0+r1)+(r2+r3))+((r4+r5)+(r6+r7))
__device__ __forceinline__ float np_sumsq64(const float* v) {
    float r[8];
#pragma unroll
    for (int j = 0; j < 8; ++j) r[j] = __fmul_rn(v[j], v[j]);
#pragma unroll
    for (int i = 8; i < 64; i += 8) {
#pragma unroll
        for (int j = 0; j < 8; ++j)
            r[j] = __fadd_rn(r[j], __fmul_rn(v[i + j], v[i + j]));
    }
    return __fadd_rn(__fadd_rn(__fadd_rn(r[0], r[1]), __fadd_rn(r[2], r[3])),
                     __fadd_rn(__fadd_rn(r[4], r[5]), __fadd_rn(r[6], r[7])));
}

// ---------------- codebook squared norms (numpy-pairwise order) ----------------
__global__ void vq_se(const float* __restrict__ cb, float* __restrict__ se) {
    int k = blockIdx.x * blockDim.x + threadIdx.x;
    if (k >= KK) return;
    float e[DD];
    const float4* p = (const float4*)(cb + (size_t)k * DD);
#pragma unroll
    for (int i = 0; i < DD / 4; ++i) {
        float4 v = p[i];
        e[4 * i + 0] = v.x; e[4 * i + 1] = v.y; e[4 * i + 2] = v.z; e[4 * i + 3] = v.w;
    }
    se[k] = np_sumsq64(e);
}

// ---------------- argmin: register-tiled 8x8 distance GEMM ----------------
// 256 threads as 16x16: tx indexes entry-groups, ty indexes row-groups.
// Thread computes an 8-row x 8-entry tile; x & e tiles in LDS, XOR-swizzled.
__global__ __launch_bounds__(256, 2)
void vq_argmin(const float* __restrict__ x, const float* __restrict__ cb,
               const float* __restrict__ se, int* __restrict__ idx,
               float* __restrict__ idx_f) {
    __shared__ float xs[BR * DD];   // 32 KB, swizzled per 16B-quad
    __shared__ float es[BC * DD];   // 32 KB, swizzled
    __shared__ float sas[BR];

    const int tid = threadIdx.x;
    const int tx = tid & 15;
    const int ty = tid >> 4;
    const int rowBase = blockIdx.x * BR;

    // ---- stage x tile (swizzled): 2048 float4, 8 per thread, coalesced reads
    {
        const float4* src = (const float4*)(x + (size_t)rowBase * DD);
        float4* dst = (float4*)xs;
#pragma unroll
        for (int j = 0; j < 8; ++j) {
            int g = j * 256 + tid;        // float4 index within tile
            int R = g >> 4, i = g & 15;
            int key = (R >> 3) & 7;
            dst[R * 16 + (i ^ key)] = src[g];
        }
    }
    __syncthreads();

    // ---- per-row ||x||^2 (numpy-pairwise), one row per (tx<8) thread
    if (tx < 8) {
        int lr = ty * 8 + tx;
        float a[DD];
        const float4* p = (const float4*)(x + (size_t)(rowBase + lr) * DD);
#pragma unroll
        for (int i = 0; i < 16; ++i) {
            float4 v = p[i];
            a[4 * i + 0] = v.x; a[4 * i + 1] = v.y; a[4 * i + 2] = v.z; a[4 * i + 3] = v.w;
        }
        sas[lr] = np_sumsq64(a);
    }

    float bestd[8];
    int   besti[8];
#pragma unroll
    for (int r = 0; r < 8; ++r) { bestd[r] = 3.4e38f; besti[r] = 0; }

    const int keyA = ty & 7;
    const int keyE = tx & 7;
    const float4* ax = (const float4*)xs + ty * 128;   // rows ty*8.. (16 quads each)
    const float4* ex = (const float4*)es + tx * 128;   // entries tx*8..

    for (int t = 0; t < NTILES; ++t) {
        __syncthreads();   // es reuse guard (also orders sas writes on t=0)
        // ---- stage codebook tile (swizzled)
        {
            const float4* src = (const float4*)(cb + (size_t)t * BC * DD);
            float4* dst = (float4*)es;
#pragma unroll
            for (int j = 0; j < 8; ++j) {
                int g = j * 256 + tid;
                int R = g >> 4, i = g & 15;
                int key = (R >> 3) & 7;
                dst[R * 16 + (i ^ key)] = src[g];
            }
        }
        __syncthreads();

        float c[8][8];
#pragma unroll
        for (int r = 0; r < 8; ++r)
#pragma unroll
            for (int q = 0; q < 8; ++q) c[r][q] = 0.f;

        // ---- 8x8 register-tile GEMM over d (sequential fma chain per (r,q))
#pragma unroll 2
        for (int i = 0; i < 16; ++i) {
            float4 a4[8], e4[8];
            int ia = i ^ keyA;
            int ie = i ^ keyE;
#pragma unroll
            for (int r = 0; r < 8; ++r) a4[r] = ax[r * 16 + ia];
#pragma unroll
            for (int q = 0; q < 8; ++q) e4[q] = ex[q * 16 + ie];
#pragma unroll
            for (int r = 0; r < 8; ++r) {
#pragma unroll
                for (int q = 0; q < 8; ++q) {
                    c[r][q] = fmaf(a4[r].x, e4[q].x, c[r][q]);
                    c[r][q] = fmaf(a4[r].y, e4[q].y, c[r][q]);
                    c[r][q] = fmaf(a4[r].z, e4[q].z, c[r][q]);
                    c[r][q] = fmaf(a4[r].w, e4[q].w, c[r][q]);
                }
            }
        }

        // ---- distances + per-thread argmin (entries ascending => first-min)
        float sev[8];
#pragma unroll
        for (int q = 0; q < 8; ++q) sev[q] = se[t * BC + tx * 8 + q];
#pragma unroll
        for (int r = 0; r < 8; ++r) {
            float sa = sas[ty * 8 + r];
#pragma unroll
            for (int q = 0; q < 8; ++q) {
                float d = __fsub_rn(__fadd_rn(sa, sev[q]), __fmul_rn(2.f, c[r][q]));
                int ke = t * BC + tx * 8 + q;
                if (d < bestd[r]) { bestd[r] = d; besti[r] = ke; }
            }
        }
    }

    // ---- cross-lane argmin over the 16 tx lanes (lexicographic => first-occurrence)
#pragma unroll
    for (int r = 0; r < 8; ++r) {
        float d = bestd[r];
        int  bi = besti[r];
#pragma unroll
        for (int off = 1; off < 16; off <<= 1) {
            float od = __shfl_xor(d, off);
            int   oi = __shfl_xor(bi, off);
            if (od < d || (od == d && oi < bi)) { d = od; bi = oi; }
        }
        if (tx == 0) {
            int grow = rowBase + ty * 8 + r;
            idx[grow]   = bi;
            idx_f[grow] = (float)bi;
        }
    }
}

// ---------------- gather + straight-through + loss partials ----------------
__global__ __launch_bounds__(256)
void vq_quant(const float* __restrict__ x, const float* __restrict__ cb,
              const int* __restrict__ idx, float* __restrict__ qout,
              double* __restrict__ acc) {
    const int nvec = NN * DD / 4;
    const int stride = gridDim.x * blockDim.x;
    float local = 0.f;
    for (int j = blockIdx.x * blockDim.x + threadIdx.x; j < nvec; j += stride) {
        int row = j >> 4;           // 16 float4 per row
        int d4  = j & 15;
        int k   = idx[row];
        float4 xv = ((const float4*)x)[j];
        float4 qv = ((const float4*)cb)[(k << 4) | d4];
        float dx = __fsub_rn(qv.x, xv.x);
        float dy = __fsub_rn(qv.y, xv.y);
        float dz = __fsub_rn(qv.z, xv.z);
        float dw = __fsub_rn(qv.w, xv.w);
        float4 o;
        o.x = __fadd_rn(xv.x, dx);
        o.y = __fadd_rn(xv.y, dy);
        o.z = __fadd_rn(xv.z, dz);
        o.w = __fadd_rn(xv.w, dw);
        ((float4*)qout)[j] = o;
        local = fmaf(dx, dx, local);
        local = fmaf(dy, dy, local);
        local = fmaf(dz, dz, local);
        local = fmaf(dw, dw, local);
    }
#pragma unroll
    for (int off = 32; off > 0; off >>= 1)
        local += __shfl_down(local, off);
    __shared__ float wsum[4];
    if ((threadIdx.x & 63) == 0) wsum[threadIdx.x >> 6] = local;
    __syncthreads();
    if (threadIdx.x == 0) {
        float s = wsum[0] + wsum[1] + wsum[2] + wsum[3];
        atomicAdd(acc, (double)s);
    }
}

// ---------------- finalize loss ----------------
__global__ void vq_loss(const double* __restrict__ acc, float* __restrict__ out) {
    out[0] = (float)(acc[0] * 1.25 / (double)((size_t)NN * DD));
}

extern "C" void kernel_launch(void* const* d_in, const int* in_sizes, int n_in,
                              void* d_out, int out_size, void* d_ws, size_t ws_size,
                              hipStream_t stream) {
    const float* x  = (const float*)d_in[0];
    const float* cb = (const float*)d_in[1];
    float* out = (float*)d_out;

    double* acc = (double*)d_ws;                      // 8B accumulator (zeroed below)
    float*  se  = (float*)((char*)d_ws + 64);         // 1024 floats
    int*    idx = (int*)((char*)d_ws + 64 + 4096);    // 131072 ints

    hipMemsetAsync(d_ws, 0, 64, stream);

    vq_se<<<4, 256, 0, stream>>>(cb, se);
    vq_argmin<<<NN / BR, 256, 0, stream>>>(x, cb, se, idx, out + 1 + (size_t)NN * DD);
    vq_quant<<<2048, 256, 0, stream>>>(x, cb, idx, out + 1, acc);
    vq_loss<<<1, 1, 0, stream>>>(acc, out);
}

// Round 6
// 237.714 us; speedup vs baseline: 2.8565x; 1.4178x over previous
//
#include <hip/hip_runtime.h>

#define NN 131072
#define DD 64
#define KK 1024

typedef __attribute__((ext_vector_type(8))) short short8v;
typedef __attribute__((ext_vector_type(4))) float float4v;
typedef __attribute__((ext_vector_type(4))) int int4v;

#define MFMA(a, b, c) __builtin_amdgcn_mfma_f32_16x16x32_bf16(a, b, c, 0, 0, 0)

// strict-< top-3 insert (k ascending arrival => first-occurrence kept on ties)
#define INS3(t0, t1, t2, i0, i1, i2, u, kk)                                  \
    if ((u) < (t0)) { t2 = t1; i2 = i1; t1 = t0; i1 = i0; t0 = (u); i0 = (kk); } \
    else if ((u) < (t1)) { t2 = t1; i2 = i1; t1 = (u); i1 = (kk); }          \
    else if ((u) < (t2)) { t2 = (u); i2 = (kk); }

// lexicographic (value, idx) top-3 insert for cross-lane merge
#define LEXINS3(t0, t1, t2, i0, i1, i2, u, kk)                               \
    if ((u) < (t0) || ((u) == (t0) && (kk) < (i0))) {                        \
        t2 = t1; i2 = i1; t1 = t0; i1 = i0; t0 = (u); i0 = (kk); }           \
    else if ((u) < (t1) || ((u) == (t1) && (kk) < (i1))) {                   \
        t2 = t1; i2 = i1; t1 = (u); i1 = (kk); }                             \
    else if ((u) < (t2) || ((u) == (t2) && (kk) < (i2))) { t2 = (u); i2 = (kk); }

// numpy pairwise sum of squares, n=64 (bit-exact vs np.sum(x**2, axis=1))
__device__ __forceinline__ float np_sumsq64(const float* v) {
    float r[8];
#pragma unroll
    for (int j = 0; j < 8; ++j) r[j] = __fmul_rn(v[j], v[j]);
#pragma unroll
    for (int i = 8; i < 64; i += 8) {
#pragma unroll
        for (int j = 0; j < 8; ++j)
            r[j] = __fadd_rn(r[j], __fmul_rn(v[i + j], v[i + j]));
    }
    return __fadd_rn(__fadd_rn(__fadd_rn(r[0], r[1]), __fadd_rn(r[2], r[3])),
                     __fadd_rn(__fadd_rn(r[4], r[5]), __fadd_rn(r[6], r[7])));
}

// RNE bf16 hi/lo split: v = hi + lo + O(2^-18 |v|); v - hi is exact in fp32
__device__ __forceinline__ void bf16split(float v, unsigned short& hb, unsigned short& lb) {
    unsigned int u = __builtin_bit_cast(unsigned int, v);
    unsigned int h = (u + 0x7FFFu + ((u >> 16) & 1u)) >> 16;
    float hf = __builtin_bit_cast(float, h << 16);
    float lo = __fsub_rn(v, hf);
    unsigned int ul = __builtin_bit_cast(unsigned int, lo);
    unsigned int lo16 = (ul + 0x7FFFu + ((ul >> 16) & 1u)) >> 16;
    hb = (unsigned short)h;
    lb = (unsigned short)lo16;
}

// ---------------- prep: codebook norms + bf16 hi/lo split ----------------
__global__ void vq_prep(const float* __restrict__ cb, unsigned short* __restrict__ cbh,
                        unsigned short* __restrict__ cbl, float* __restrict__ se) {
    int k = blockIdx.x * 256 + threadIdx.x;
    if (k >= KK) return;
    float v[DD];
    const float4* p = (const float4*)(cb + (size_t)k * DD);
#pragma unroll
    for (int i = 0; i < 16; ++i) {
        float4 q = p[i];
        v[4 * i + 0] = q.x; v[4 * i + 1] = q.y; v[4 * i + 2] = q.z; v[4 * i + 3] = q.w;
    }
    se[k] = np_sumsq64(v);
    short8v* oh = (short8v*)(cbh + (size_t)k * DD);
    short8v* ol = (short8v*)(cbl + (size_t)k * DD);
#pragma unroll
    for (int q = 0; q < 8; ++q) {
        short8v hq, lq;
#pragma unroll
        for (int e = 0; e < 8; ++e) {
            unsigned short hb, lb;
            bf16split(v[q * 8 + e], hb, lb);
            hq[e] = (short)hb; lq[e] = (short)lb;
        }
        oh[q] = hq; ol[q] = lq;
    }
}

// ---------------- main: MFMA screen + exact rescore + quantize/loss ----------------
// 256 threads = 4 waves; 128 rows/block (32 rows/wave as 2 MFMA row-sets); 1024 blocks.
__global__ __launch_bounds__(256)
void vq_main(const float* __restrict__ x, const float* __restrict__ cb,
             const unsigned short* __restrict__ cbh, const unsigned short* __restrict__ cbl,
             const float* __restrict__ se, float* __restrict__ qout,
             float* __restrict__ idxf, double* __restrict__ acc) {
    __shared__ unsigned short xh[128 * 64], xl[128 * 64];   // 16 KB each, swizzled quads
    __shared__ unsigned short ebh[128 * 64], ebl[128 * 64]; // 16 KB each, swizzled quads
    __shared__ float ses[KK];                               // 4 KB
    __shared__ float wls[4];

    const int tid = threadIdx.x;
    const int rowBase = blockIdx.x * 128;
    const int l = tid & 63;     // lane
    const int w = tid >> 6;     // wave 0..3
    const int col = l & 15;
    const int g = l >> 4;       // 16-lane group 0..3

    // ---- stage se -> LDS
    ((float4v*)ses)[tid] = ((const float4v*)se)[tid];

    // ---- convert x tile to bf16 hi/lo, swizzled LDS store
    {
        int row = tid >> 1, db = (tid & 1) * 32;
        const float* xr = x + (size_t)(rowBase + row) * 64 + db;
#pragma unroll
        for (int jj = 0; jj < 4; ++jj) {
            float4 v0 = ((const float4*)xr)[2 * jj];
            float4 v1 = ((const float4*)xr)[2 * jj + 1];
            float vv[8] = {v0.x, v0.y, v0.z, v0.w, v1.x, v1.y, v1.z, v1.w};
            short8v hq, lq;
#pragma unroll
            for (int e = 0; e < 8; ++e) {
                unsigned short hb, lb;
                bf16split(vv[e], hb, lb);
                hq[e] = (short)hb; lq[e] = (short)lb;
            }
            int q = (tid & 1) * 4 + jj;
            int slot = row * 8 + (q ^ (row & 7));
            ((short8v*)xh)[slot] = hq;
            ((short8v*)xl)[slot] = lq;
        }
    }
    __syncthreads();

    // ---- A fragments (held whole kernel): rows w*32+col (set0), +16 (set1)
    short8v ah0s0, ah1s0, al0s0, al1s0, ah0s1, ah1s1, al0s1, al1s1;
    {
        int r0 = w * 32 + col;
        int r1 = r0 + 16;
        ah0s0 = ((short8v*)xh)[r0 * 8 + ((0 + g) ^ (r0 & 7))];
        ah1s0 = ((short8v*)xh)[r0 * 8 + ((4 + g) ^ (r0 & 7))];
        al0s0 = ((short8v*)xl)[r0 * 8 + ((0 + g) ^ (r0 & 7))];
        al1s0 = ((short8v*)xl)[r0 * 8 + ((4 + g) ^ (r0 & 7))];
        ah0s1 = ((short8v*)xh)[r1 * 8 + ((0 + g) ^ (r1 & 7))];
        ah1s1 = ((short8v*)xh)[r1 * 8 + ((4 + g) ^ (r1 & 7))];
        al0s1 = ((short8v*)xl)[r1 * 8 + ((0 + g) ^ (r1 & 7))];
        al1s1 = ((short8v*)xl)[r1 * 8 + ((4 + g) ^ (r1 & 7))];
    }

    // ---- per-(lane,row-slot) top-3 screen state
    float bt[8][3];
    int bix[8][3];
#pragma unroll
    for (int s = 0; s < 8; ++s) {
#pragma unroll
        for (int j = 0; j < 3; ++j) { bt[s][j] = 3.4e38f; bix[s][j] = 0x7FFFFFF; }
    }

    // ---- B tile staging regs (T14: issue-early / write-late)
    int4v rbh[4], rbl[4];
    {
        int e = tid >> 1;
        const unsigned short* ph = cbh + (size_t)e * 64 + (tid & 1) * 32;
        const unsigned short* pl = cbl + (size_t)e * 64 + (tid & 1) * 32;
#pragma unroll
        for (int jj = 0; jj < 4; ++jj) {
            rbh[jj] = *(const int4v*)(ph + jj * 8);
            rbl[jj] = *(const int4v*)(pl + jj * 8);
        }
    }

    for (int t = 0; t < 8; ++t) {
        __syncthreads();
        // write staged regs -> LDS (swizzled)
        {
            int e = tid >> 1;
#pragma unroll
            for (int jj = 0; jj < 4; ++jj) {
                int q = (tid & 1) * 4 + jj;
                int slot = e * 8 + (q ^ (e & 7));
                ((int4v*)ebh)[slot] = rbh[jj];
                ((int4v*)ebl)[slot] = rbl[jj];
            }
        }
        __syncthreads();
        if (t < 7) {
            int e = tid >> 1;
            const unsigned short* ph = cbh + (size_t)((t + 1) * 128 + e) * 64 + (tid & 1) * 32;
            const unsigned short* pl = cbl + (size_t)((t + 1) * 128 + e) * 64 + (tid & 1) * 32;
#pragma unroll
            for (int jj = 0; jj < 4; ++jj) {
                rbh[jj] = *(const int4v*)(ph + jj * 8);
                rbl[jj] = *(const int4v*)(pl + jj * 8);
            }
        }

#pragma unroll
        for (int c = 0; c < 8; ++c) {
            int ec = c * 16 + col;
            int be = ec * 8, sw = ec & 7;
            short8v bh0 = ((short8v*)ebh)[be + ((0 + g) ^ sw)];
            short8v bh1 = ((short8v*)ebh)[be + ((4 + g) ^ sw)];
            short8v bl0 = ((short8v*)ebl)[be + ((0 + g) ^ sw)];
            short8v bl1 = ((short8v*)ebl)[be + ((4 + g) ^ sw)];
            float sek = ses[t * 128 + ec];
            float4v acc0 = {0.f, 0.f, 0.f, 0.f}, acc1 = {0.f, 0.f, 0.f, 0.f};
            acc0 = MFMA(ah0s0, bh0, acc0);
            acc0 = MFMA(ah1s0, bh1, acc0);
            acc0 = MFMA(al0s0, bh0, acc0);
            acc0 = MFMA(al1s0, bh1, acc0);
            acc0 = MFMA(ah0s0, bl0, acc0);
            acc0 = MFMA(ah1s0, bl1, acc0);
            acc1 = MFMA(ah0s1, bh0, acc1);
            acc1 = MFMA(ah1s1, bh1, acc1);
            acc1 = MFMA(al0s1, bh0, acc1);
            acc1 = MFMA(al1s1, bh1, acc1);
            acc1 = MFMA(ah0s1, bl0, acc1);
            acc1 = MFMA(ah1s1, bl1, acc1);
            int kk = t * 128 + ec;
#pragma unroll
            for (int r = 0; r < 4; ++r) {
                float u0 = fmaf(-2.f, acc0[r], sek);
                INS3(bt[r][0], bt[r][1], bt[r][2], bix[r][0], bix[r][1], bix[r][2], u0, kk);
                float u1 = fmaf(-2.f, acc1[r], sek);
                INS3(bt[4 + r][0], bt[4 + r][1], bt[4 + r][2],
                     bix[4 + r][0], bix[4 + r][1], bix[4 + r][2], u1, kk);
            }
        }
    }

    // ---- merge top-3 across the 16 lanes of each group (butterfly, lexicographic)
#pragma unroll
    for (int s = 0; s < 8; ++s) {
#pragma unroll
        for (int m = 1; m < 16; m <<= 1) {
            float o0 = __shfl_xor(bt[s][0], m), o1 = __shfl_xor(bt[s][1], m), o2 = __shfl_xor(bt[s][2], m);
            int q0 = __shfl_xor(bix[s][0], m), q1 = __shfl_xor(bix[s][1], m), q2 = __shfl_xor(bix[s][2], m);
            LEXINS3(bt[s][0], bt[s][1], bt[s][2], bix[s][0], bix[s][1], bix[s][2], o0, q0);
            LEXINS3(bt[s][0], bt[s][1], bt[s][2], bix[s][0], bix[s][1], bix[s][2], o1, q1);
            LEXINS3(bt[s][0], bt[s][1], bt[s][2], bix[s][0], bix[s][1], bix[s][2], o2, q2);
        }
    }

    // ---- exact rescore + quantize/st/loss (2 passes: row sets 0,1)
    float lossLocal = 0.f;
    const int rr = (l & 15) >> 2;  // row-in-group
    const int j = l & 3;           // candidate slot (3 => duplicate 0)
    const int jj = (j == 3) ? 0 : j;
#pragma unroll
    for (int s = 0; s < 2; ++s) {
        int ck = bix[s * 4][0];
#pragma unroll
        for (int r_ = 0; r_ < 4; ++r_) {
#pragma unroll
            for (int j_ = 0; j_ < 3; ++j_) {
                if (rr == r_ && jj == j_) ck = bix[s * 4 + r_][j_];
            }
        }
        int rowg = rowBase + w * 32 + s * 16 + g * 4 + rr;
        const float4* xr = (const float4*)(x + (size_t)rowg * 64);
        const float4* er = (const float4*)(cb + (size_t)ck * 64);
        // exact dot (sequential fma, d ascending) + numpy-pairwise ||x||^2
        float dot = 0.f;
        float rs0 = 0.f, rs1 = 0.f, rs2 = 0.f, rs3 = 0.f, rs4 = 0.f, rs5 = 0.f, rs6 = 0.f, rs7 = 0.f;
#pragma unroll
        for (int i = 0; i < 16; ++i) {
            float4 a4 = xr[i], e4 = er[i];
            dot = fmaf(a4.x, e4.x, dot);
            dot = fmaf(a4.y, e4.y, dot);
            dot = fmaf(a4.z, e4.z, dot);
            dot = fmaf(a4.w, e4.w, dot);
            if ((i & 1) == 0) {
                rs0 = __fadd_rn(rs0, __fmul_rn(a4.x, a4.x));
                rs1 = __fadd_rn(rs1, __fmul_rn(a4.y, a4.y));
                rs2 = __fadd_rn(rs2, __fmul_rn(a4.z, a4.z));
                rs3 = __fadd_rn(rs3, __fmul_rn(a4.w, a4.w));
            } else {
                rs4 = __fadd_rn(rs4, __fmul_rn(a4.x, a4.x));
                rs5 = __fadd_rn(rs5, __fmul_rn(a4.y, a4.y));
                rs6 = __fadd_rn(rs6, __fmul_rn(a4.z, a4.z));
                rs7 = __fadd_rn(rs7, __fmul_rn(a4.w, a4.w));
            }
        }
        float sa = __fadd_rn(__fadd_rn(__fadd_rn(rs0, rs1), __fadd_rn(rs2, rs3)),
                             __fadd_rn(__fadd_rn(rs4, rs5), __fadd_rn(rs6, rs7)));
        float qd = __fsub_rn(__fadd_rn(sa, ses[ck]), __fmul_rn(2.f, dot));
        // lexicographic (qd, k) min over the 3 candidate lanes
#pragma unroll
        for (int m = 1; m < 4; m <<= 1) {
            float oq = __shfl_xor(qd, m);
            int ok = __shfl_xor(ck, m);
            if (oq < qd || (oq == qd && ok < ck)) { qd = oq; ck = ok; }
        }
        if (j == 0) idxf[rowg] = (float)ck;
        // quantize + straight-through + loss partial (lane j handles quads j*4..j*4+3)
        const float4* qr = (const float4*)(cb + (size_t)ck * 64);
        float* orow = qout + (size_t)rowg * 64;
#pragma unroll
        for (int p = 0; p < 4; ++p) {
            int iq = j * 4 + p;
            float4 xv = xr[iq];
            float4 qv = qr[iq];
            float dx = __fsub_rn(qv.x, xv.x);
            float dy = __fsub_rn(qv.y, xv.y);
            float dz = __fsub_rn(qv.z, xv.z);
            float dw = __fsub_rn(qv.w, xv.w);
            float4 o;
            o.x = __fadd_rn(xv.x, dx);
            o.y = __fadd_rn(xv.y, dy);
            o.z = __fadd_rn(xv.z, dz);
            o.w = __fadd_rn(xv.w, dw);
            ((float4*)orow)[iq] = o;
            lossLocal = fmaf(dx, dx, lossLocal);
            lossLocal = fmaf(dy, dy, lossLocal);
            lossLocal = fmaf(dz, dz, lossLocal);
            lossLocal = fmaf(dw, dw, lossLocal);
        }
    }
    // ---- block loss reduction -> one double atomic
#pragma unroll
    for (int m = 1; m < 64; m <<= 1) lossLocal += __shfl_xor(lossLocal, m);
    if (l == 0) wls[w] = lossLocal;
    __syncthreads();
    if (tid == 0) atomicAdd(acc, (double)(wls[0] + wls[1] + wls[2] + wls[3]));
}

// ---------------- finalize loss ----------------
__global__ void vq_loss(const double* __restrict__ acc, float* __restrict__ out) {
    out[0] = (float)(acc[0] * 1.25 / (double)((size_t)NN * DD));
}

extern "C" void kernel_launch(void* const* d_in, const int* in_sizes, int n_in,
                              void* d_out, int out_size, void* d_ws, size_t ws_size,
                              hipStream_t stream) {
    const float* x = (const float*)d_in[0];
    const float* cb = (const float*)d_in[1];
    float* out = (float*)d_out;

    double* acc = (double*)d_ws;                               // 8 B
    float* se = (float*)((char*)d_ws + 64);                    // 4 KB
    unsigned short* cbh = (unsigned short*)((char*)d_ws + 8192);      // 128 KB
    unsigned short* cbl = (unsigned short*)((char*)d_ws + 8192 + 131072); // 128 KB

    hipMemsetAsync(d_ws, 0, 64, stream);

    vq_prep<<<4, 256, 0, stream>>>(cb, cbh, cbl, se);
    vq_main<<<NN / 128, 256, 0, stream>>>(x, cb, cbh, cbl, se,
                                          out + 1, out + 1 + (size_t)NN * DD, acc);
    vq_loss<<<1, 1, 0, stream>>>(acc, out);
}

// Round 8
// 195.389 us; speedup vs baseline: 3.4753x; 1.2166x over previous
//
#include <hip/hip_runtime.h>

#define NN 131072
#define DD 64
#define KK 1024

typedef __attribute__((ext_vector_type(8))) short short8v;
typedef __attribute__((ext_vector_type(4))) float float4v;
typedef __attribute__((ext_vector_type(4))) int int4v;

#define MFMA(a, b, c) __builtin_amdgcn_mfma_f32_16x16x32_bf16(a, b, c, 0, 0, 0)

__device__ __forceinline__ unsigned int umin32(unsigned int a, unsigned int b) { return a < b ? a : b; }
__device__ __forceinline__ unsigned int umax32(unsigned int a, unsigned int b) { return a > b ? a : b; }

// order-preserving float->uint, top 22 bits kept, 10-bit index in low bits.
// min over packed keys == lexicographic (quantized value, index) min.
__device__ __forceinline__ unsigned int packu(float u, int kk) {
    int b = __builtin_bit_cast(int, u);
    unsigned int key = (unsigned int)(b ^ ((b >> 31) | 0x80000000));
    return (key & 0xFFFFFC00u) | (unsigned int)kk;
}

// sorted-insert p into ascending triple (5 min/max)
#define PINS3(t0, t1, t2, p)                                   \
    { unsigned int _x0 = umax32(t0, p); t0 = umin32(t0, p);    \
      unsigned int _x1 = umax32(t1, _x0); t1 = umin32(t1, _x0);\
      t2 = umin32(t2, _x1); }

// numpy pairwise sum of squares, n=64 (bit-exact vs np.sum(x**2, axis=1))
__device__ __forceinline__ float np_sumsq64(const float* v) {
    float r[8];
#pragma unroll
    for (int j = 0; j < 8; ++j) r[j] = __fmul_rn(v[j], v[j]);
#pragma unroll
    for (int i = 8; i < 64; i += 8) {
#pragma unroll
        for (int j = 0; j < 8; ++j)
            r[j] = __fadd_rn(r[j], __fmul_rn(v[i + j], v[i + j]));
    }
    return __fadd_rn(__fadd_rn(__fadd_rn(r[0], r[1]), __fadd_rn(r[2], r[3])),
                     __fadd_rn(__fadd_rn(r[4], r[5]), __fadd_rn(r[6], r[7])));
}

// RNE bf16 hi/lo split: v = hi + lo + O(2^-18 |v|)
__device__ __forceinline__ void bf16split(float v, unsigned short& hb, unsigned short& lb) {
    unsigned int u = __builtin_bit_cast(unsigned int, v);
    unsigned int h = (u + 0x7FFFu + ((u >> 16) & 1u)) >> 16;
    float hf = __builtin_bit_cast(float, h << 16);
    float lo = __fsub_rn(v, hf);
    unsigned int ul = __builtin_bit_cast(unsigned int, lo);
    unsigned int lo16 = (ul + 0x7FFFu + ((ul >> 16) & 1u)) >> 16;
    hb = (unsigned short)h;
    lb = (unsigned short)lo16;
}

// ---------------- prep: codebook norms + bf16 hi/lo split ----------------
__global__ void vq_prep(const float* __restrict__ cb, unsigned short* __restrict__ cbh,
                        unsigned short* __restrict__ cbl, float* __restrict__ se) {
    int k = blockIdx.x * 256 + threadIdx.x;
    if (k >= KK) return;
    float v[DD];
    const float4* p = (const float4*)(cb + (size_t)k * DD);
#pragma unroll
    for (int i = 0; i < 16; ++i) {
        float4 q = p[i];
        v[4 * i + 0] = q.x; v[4 * i + 1] = q.y; v[4 * i + 2] = q.z; v[4 * i + 3] = q.w;
    }
    se[k] = np_sumsq64(v);
    short8v* oh = (short8v*)(cbh + (size_t)k * DD);
    short8v* ol = (short8v*)(cbl + (size_t)k * DD);
#pragma unroll
    for (int q = 0; q < 8; ++q) {
        short8v hq, lq;
#pragma unroll
        for (int e = 0; e < 8; ++e) {
            unsigned short hb, lb;
            bf16split(v[q * 8 + e], hb, lb);
            hq[e] = (short)hb; lq[e] = (short)lb;
        }
        oh[q] = hq; ol[q] = lq;
    }
}

// ---------------- main: MFMA screen + exact rescore + quantize/loss ----------------
// 256 threads = 4 waves; 128 rows/block; 1024 blocks. LDS ~37 KB -> 4 blocks/CU.
union SMem {
    struct { unsigned short xh[128 * 64]; unsigned short xl[128 * 64]; } x;  // 32 KB
    struct { unsigned short bh[2][64 * 64]; unsigned short bl[2][64 * 64]; } b;  // 32 KB
};

__global__ __launch_bounds__(256, 4)
void vq_main(const float* __restrict__ x, const float* __restrict__ cb,
             const unsigned short* __restrict__ cbh, const unsigned short* __restrict__ cbl,
             const float* __restrict__ se, float* __restrict__ qout,
             float* __restrict__ idxf, double* __restrict__ acc) {
    __shared__ SMem sm;
    __shared__ float ses[KK];
    __shared__ float wls[4];

    const int tid = threadIdx.x;
    const int rowBase = blockIdx.x * 128;
    const int l = tid & 63;
    const int w = tid >> 6;
    const int col = l & 15;
    const int g = l >> 4;

    // ---- B tile staging regs (16 VGPRs)
    int4v rbh[2], rbl[2];
    const int be_ = tid >> 2;            // entry 0..63
    const int bq_ = (tid & 3) * 2;       // first of 2 quads
#define LOAD_TILE(tt)                                                              \
    { const unsigned short* ph = cbh + ((size_t)((tt) * 64 + be_) * 64) + (tid & 3) * 16; \
      const unsigned short* pl = cbl + ((size_t)((tt) * 64 + be_) * 64) + (tid & 3) * 16; \
      rbh[0] = *(const int4v*)(ph); rbh[1] = *(const int4v*)(ph + 8);              \
      rbl[0] = *(const int4v*)(pl); rbl[1] = *(const int4v*)(pl + 8); }
#define WRITE_TILE(bufi)                                                           \
    { int4v* dh = (int4v*)sm.b.bh[bufi]; int4v* dl = (int4v*)sm.b.bl[bufi];        \
      dh[be_ * 8 + (bq_ ^ (be_ & 7))] = rbh[0];                                    \
      dh[be_ * 8 + ((bq_ + 1) ^ (be_ & 7))] = rbh[1];                              \
      dl[be_ * 8 + (bq_ ^ (be_ & 7))] = rbl[0];                                    \
      dl[be_ * 8 + ((bq_ + 1) ^ (be_ & 7))] = rbl[1]; }

    // ---- stage se -> LDS
    ((float4v*)ses)[tid] = ((const float4v*)se)[tid];

    // ---- convert x tile to bf16 hi/lo, swizzled LDS store
    {
        int row = tid >> 1, db = (tid & 1) * 32;
        const float* xr = x + (size_t)(rowBase + row) * 64 + db;
#pragma unroll
        for (int jj = 0; jj < 4; ++jj) {
            float4 v0 = ((const float4*)xr)[2 * jj];
            float4 v1 = ((const float4*)xr)[2 * jj + 1];
            float vv[8] = {v0.x, v0.y, v0.z, v0.w, v1.x, v1.y, v1.z, v1.w};
            short8v hq, lq;
#pragma unroll
            for (int e = 0; e < 8; ++e) {
                unsigned short hb, lb;
                bf16split(vv[e], hb, lb);
                hq[e] = (short)hb; lq[e] = (short)lb;
            }
            int q = (tid & 1) * 4 + jj;
            int slot = row * 8 + (q ^ (row & 7));
            ((short8v*)sm.x.xh)[slot] = hq;
            ((short8v*)sm.x.xl)[slot] = lq;
        }
    }
    LOAD_TILE(0);
    __syncthreads();

    // ---- A fragments (held whole kernel): rows w*32+col (set0), +16 (set1)
    short8v ah0s0, ah1s0, al0s0, al1s0, ah0s1, ah1s1, al0s1, al1s1;
    {
        int r0 = w * 32 + col;
        int r1 = r0 + 16;
        ah0s0 = ((short8v*)sm.x.xh)[r0 * 8 + ((0 + g) ^ (r0 & 7))];
        ah1s0 = ((short8v*)sm.x.xh)[r0 * 8 + ((4 + g) ^ (r0 & 7))];
        al0s0 = ((short8v*)sm.x.xl)[r0 * 8 + ((0 + g) ^ (r0 & 7))];
        al1s0 = ((short8v*)sm.x.xl)[r0 * 8 + ((4 + g) ^ (r0 & 7))];
        ah0s1 = ((short8v*)sm.x.xh)[r1 * 8 + ((0 + g) ^ (r1 & 7))];
        ah1s1 = ((short8v*)sm.x.xh)[r1 * 8 + ((4 + g) ^ (r1 & 7))];
        al0s1 = ((short8v*)sm.x.xl)[r1 * 8 + ((0 + g) ^ (r1 & 7))];
        al1s1 = ((short8v*)sm.x.xl)[r1 * 8 + ((4 + g) ^ (r1 & 7))];
    }
    __syncthreads();   // A-frags consumed; x region free for B tiles

    WRITE_TILE(0);
    LOAD_TILE(1);
    __syncthreads();

    // ---- packed top-3 screen state (24 VGPRs)
    unsigned int k0[8], k1[8], k2[8];
#pragma unroll
    for (int s = 0; s < 8; ++s) { k0[s] = 0xFFFFFFFFu; k1[s] = 0xFFFFFFFFu; k2[s] = 0xFFFFFFFFu; }

    for (int t = 0; t < 16; ++t) {
        if (t < 15) {
            WRITE_TILE((t + 1) & 1);     // regs hold tile t+1 -> alt buffer
            if (t < 14) LOAD_TILE(t + 2);
        }
        const unsigned short* bhB = sm.b.bh[t & 1];
        const unsigned short* blB = sm.b.bl[t & 1];
#pragma unroll
        for (int c = 0; c < 4; ++c) {
            int ec = c * 16 + col;
            int be = ec * 8, sw = ec & 7;
            short8v bh0 = ((const short8v*)bhB)[be + ((0 + g) ^ sw)];
            short8v bh1 = ((const short8v*)bhB)[be + ((4 + g) ^ sw)];
            short8v bl0 = ((const short8v*)blB)[be + ((0 + g) ^ sw)];
            short8v bl1 = ((const short8v*)blB)[be + ((4 + g) ^ sw)];
            float sek = ses[t * 64 + ec];
            float4v acc0 = {0.f, 0.f, 0.f, 0.f}, acc1 = {0.f, 0.f, 0.f, 0.f};
            acc0 = MFMA(ah0s0, bh0, acc0);
            acc0 = MFMA(ah1s0, bh1, acc0);
            acc0 = MFMA(al0s0, bh0, acc0);
            acc0 = MFMA(al1s0, bh1, acc0);
            acc0 = MFMA(ah0s0, bl0, acc0);
            acc0 = MFMA(ah1s0, bl1, acc0);
            acc1 = MFMA(ah0s1, bh0, acc1);
            acc1 = MFMA(ah1s1, bh1, acc1);
            acc1 = MFMA(al0s1, bh0, acc1);
            acc1 = MFMA(al1s1, bh1, acc1);
            acc1 = MFMA(ah0s1, bl0, acc1);
            acc1 = MFMA(ah1s1, bl1, acc1);
            int kk = t * 64 + ec;
#pragma unroll
            for (int r = 0; r < 4; ++r) {
                unsigned int p0 = packu(fmaf(-2.f, acc0[r], sek), kk);
                PINS3(k0[r], k1[r], k2[r], p0);
                unsigned int p1 = packu(fmaf(-2.f, acc1[r], sek), kk);
                PINS3(k0[4 + r], k1[4 + r], k2[4 + r], p1);
            }
        }
        __syncthreads();
    }

    // ---- merge top-3 across the 16 lanes of each group (sorted-merge, 9 ops/step)
#pragma unroll
    for (int s = 0; s < 8; ++s) {
#pragma unroll
        for (int m = 1; m < 16; m <<= 1) {
            unsigned int o0 = __shfl_xor(k0[s], m);
            unsigned int o1 = __shfl_xor(k1[s], m);
            unsigned int o2 = __shfl_xor(k2[s], m);
            PINS3(k0[s], k1[s], k2[s], o0);
            { unsigned int x1 = umax32(k1[s], o1); k1[s] = umin32(k1[s], o1);
              k2[s] = umin32(k2[s], x1); }
            k2[s] = umin32(k2[s], o2);
        }
    }

    // ---- exact rescore + quantize/st/loss (2 passes: row sets 0,1)
    float lossLocal = 0.f;
    const int rr = (l & 15) >> 2;  // row-in-group
    const int j = l & 3;           // candidate slot (3 => duplicate 0)
    const int jj = (j == 3) ? 0 : j;
#pragma unroll
    for (int s = 0; s < 2; ++s) {
        unsigned int ckk = k0[s * 4];
#pragma unroll
        for (int r_ = 0; r_ < 4; ++r_) {
            if (rr == r_) {
                if (jj == 0) ckk = k0[s * 4 + r_];
                else if (jj == 1) ckk = k1[s * 4 + r_];
                else ckk = k2[s * 4 + r_];
            }
        }
        int ck = (int)(ckk & 1023u);
        int rowg = rowBase + w * 32 + s * 16 + g * 4 + rr;
        const float4* xr = (const float4*)(x + (size_t)rowg * 64);
        const float4* er = (const float4*)(cb + (size_t)ck * 64);
        // exact dot (sequential fma, d ascending) + numpy-pairwise ||x||^2
        float dot = 0.f;
        float rs0 = 0.f, rs1 = 0.f, rs2 = 0.f, rs3 = 0.f, rs4 = 0.f, rs5 = 0.f, rs6 = 0.f, rs7 = 0.f;
#pragma unroll
        for (int i = 0; i < 16; ++i) {
            float4 a4 = xr[i], e4 = er[i];
            dot = fmaf(a4.x, e4.x, dot);
            dot = fmaf(a4.y, e4.y, dot);
            dot = fmaf(a4.z, e4.z, dot);
            dot = fmaf(a4.w, e4.w, dot);
            if ((i & 1) == 0) {
                rs0 = __fadd_rn(rs0, __fmul_rn(a4.x, a4.x));
                rs1 = __fadd_rn(rs1, __fmul_rn(a4.y, a4.y));
                rs2 = __fadd_rn(rs2, __fmul_rn(a4.z, a4.z));
                rs3 = __fadd_rn(rs3, __fmul_rn(a4.w, a4.w));
            } else {
                rs4 = __fadd_rn(rs4, __fmul_rn(a4.x, a4.x));
                rs5 = __fadd_rn(rs5, __fmul_rn(a4.y, a4.y));
                rs6 = __fadd_rn(rs6, __fmul_rn(a4.z, a4.z));
                rs7 = __fadd_rn(rs7, __fmul_rn(a4.w, a4.w));
            }
        }
        float sa = __fadd_rn(__fadd_rn(__fadd_rn(rs0, rs1), __fadd_rn(rs2, rs3)),
                             __fadd_rn(__fadd_rn(rs4, rs5), __fadd_rn(rs6, rs7)));
        float qd = __fsub_rn(__fadd_rn(sa, ses[ck]), __fmul_rn(2.f, dot));
        // lexicographic (qd, k) min over the candidate lanes
#pragma unroll
        for (int m = 1; m < 4; m <<= 1) {
            float oq = __shfl_xor(qd, m);
            int ok = __shfl_xor(ck, m);
            if (oq < qd || (oq == qd && ok < ck)) { qd = oq; ck = ok; }
        }
        if (j == 0) idxf[rowg] = (float)ck;
        // quantize + straight-through + loss partial (lane j handles quads j*4..j*4+3)
        const float4* qr = (const float4*)(cb + (size_t)ck * 64);
        float* orow = qout + (size_t)rowg * 64;
#pragma unroll
        for (int p = 0; p < 4; ++p) {
            int iq = j * 4 + p;
            float4 xv = xr[iq];
            float4 qv = qr[iq];
            float dx = __fsub_rn(qv.x, xv.x);
            float dy = __fsub_rn(qv.y, xv.y);
            float dz = __fsub_rn(qv.z, xv.z);
            float dw = __fsub_rn(qv.w, xv.w);
            float4 o;
            o.x = __fadd_rn(xv.x, dx);
            o.y = __fadd_rn(xv.y, dy);
            o.z = __fadd_rn(xv.z, dz);
            o.w = __fadd_rn(xv.w, dw);
            ((float4*)orow)[iq] = o;
            lossLocal = fmaf(dx, dx, lossLocal);
            lossLocal = fmaf(dy, dy, lossLocal);
            lossLocal = fmaf(dz, dz, lossLocal);
            lossLocal = fmaf(dw, dw, lossLocal);
        }
    }
    // ---- block loss reduction -> one double atomic
#pragma unroll
    for (int m = 1; m < 64; m <<= 1) lossLocal += __shfl_xor(lossLocal, m);
    if (l == 0) wls[w] = lossLocal;
    __syncthreads();
    if (tid == 0) atomicAdd(acc, (double)(wls[0] + wls[1] + wls[2] + wls[3]));
}

// ---------------- finalize loss ----------------
__global__ void vq_loss(const double* __restrict__ acc, float* __restrict__ out) {
    out[0] = (float)(acc[0] * 1.25 / (double)((size_t)NN * DD));
}

extern "C" void kernel_launch(void* const* d_in, const int* in_sizes, int n_in,
                              void* d_out, int out_size, void* d_ws, size_t ws_size,
                              hipStream_t stream) {
    const float* x = (const float*)d_in[0];
    const float* cb = (const float*)d_in[1];
    float* out = (float*)d_out;

    double* acc = (double*)d_ws;                               // 8 B
    float* se = (float*)((char*)d_ws + 64);                    // 4 KB
    unsigned short* cbh = (unsigned short*)((char*)d_ws + 8192);      // 128 KB
    unsigned short* cbl = (unsigned short*)((char*)d_ws + 8192 + 131072); // 128 KB

    hipMemsetAsync(d_ws, 0, 64, stream);

    vq_prep<<<4, 256, 0, stream>>>(cb, cbh, cbl, se);
    vq_main<<<NN / 128, 256, 0, stream>>>(x, cb, cbh, cbl, se,
                                          out + 1, out + 1 + (size_t)NN * DD, acc);
    vq_loss<<<1, 1, 0, stream>>>(acc, out);
}